// Round 1
// baseline (6674.817 us; speedup 1.0000x reference)
//
#include <hip/hip_runtime.h>
#include <hip/hip_bf16.h>
#include <cstdint>
#include <cstddef>

#define B_   512
#define T_   128
#define D_   512
#define H_   512
#define MID_ 38
#define BOT_ 38
#define S_   26
#define XL_  588   // D + MID + BOT = W_ih row length

__device__ __forceinline__ float sigmoidf_(float x){ return 1.0f/(1.0f+expf(-x)); }

// ---------------------------------------------------------------------------
// Generic fp32 GEMM:  C[m,n] = sum_k A[m,k]*Bw[n,k]  (+ optional second phase
// with A2/Bw2 over the same K, + optional bias/bias2).  NT layout, row-major.
// blockDim = 256 = (BM/TM)*(BN/TN).
// ---------------------------------------------------------------------------
template<int BM,int BN,int BK,int TM,int TN>
__global__ __launch_bounds__(256) void sgemm_nt(
    const float* __restrict__ A,  int lda,
    const float* __restrict__ Bw, int ldb,
    const float* __restrict__ A2, int lda2,
    const float* __restrict__ Bw2,int ldb2,
    const float* __restrict__ bias, const float* __restrict__ bias2,
    float* __restrict__ C, int M, int N, int K, int nPhases)
{
  constexpr int PAD = 4;
  __shared__ float As[BK][BM+PAD];
  __shared__ float Bs[BK][BN+PAD];
  const int tid = threadIdx.x;
  const int bm = blockIdx.y * BM;
  const int bn = blockIdx.x * BN;
  constexpr int NX = BN/TN;
  const int tx = tid % NX;
  const int ty = tid / NX;

  float acc[TM][TN];
#pragma unroll
  for (int i=0;i<TM;i++)
#pragma unroll
    for (int j=0;j<TN;j++) acc[i][j]=0.f;

  constexpr int AF4 = BM*BK/1024;  // float4 loads per thread for A tile
  constexpr int BF4 = BN*BK/1024;
  constexpr int K4  = BK/4;

  for (int ph=0; ph<nPhases; ++ph){
    const float* Ap = ph ? A2  : A;   const int ldA = ph ? lda2 : lda;
    const float* Bp = ph ? Bw2 : Bw;  const int ldB = ph ? ldb2 : ldb;
    for (int kk=0; kk<K; kk+=BK){
      __syncthreads();
#pragma unroll
      for (int i=0;i<AF4;i++){
        int idx = tid + i*256;
        int row = idx / K4, c4 = idx % K4;
        const float4 v = *reinterpret_cast<const float4*>(
            &Ap[(size_t)(bm+row)*ldA + kk + c4*4]);
        As[c4*4+0][row]=v.x; As[c4*4+1][row]=v.y;
        As[c4*4+2][row]=v.z; As[c4*4+3][row]=v.w;
      }
#pragma unroll
      for (int i=0;i<BF4;i++){
        int idx = tid + i*256;
        int row = idx / K4, c4 = idx % K4;
        const float4 v = *reinterpret_cast<const float4*>(
            &Bp[(size_t)(bn+row)*ldB + kk + c4*4]);
        Bs[c4*4+0][row]=v.x; Bs[c4*4+1][row]=v.y;
        Bs[c4*4+2][row]=v.z; Bs[c4*4+3][row]=v.w;
      }
      __syncthreads();
#pragma unroll
      for (int k=0;k<BK;k++){
        float a[TM], b[TN];
#pragma unroll
        for (int i=0;i<TM;i++) a[i] = As[k][ty*TM+i];
#pragma unroll
        for (int j=0;j<TN;j++) b[j] = Bs[k][tx*TN+j];
#pragma unroll
        for (int i=0;i<TM;i++)
#pragma unroll
          for (int j=0;j<TN;j++) acc[i][j] += a[i]*b[j];
      }
    }
  }
#pragma unroll
  for (int i=0;i<TM;i++){
    const int m = bm + ty*TM + i;
#pragma unroll
    for (int j=0;j<TN;j++){
      const int n = bn + tx*TN + j;
      float v = acc[i][j];
      if (bias)  v += bias[n];
      if (bias2) v += bias2[n];
      C[(size_t)m*N + n] = v;
    }
  }
}

// ---------------------------------------------------------------------------
// Fused attention: per block b — e[t] = sum_h Ws[h]*tanh(proj[b,t,h]+pp[b,h]),
// softmax over t, context[b,d] = sum_t alpha[t]*batch_H[b,t,d].
// ---------------------------------------------------------------------------
__global__ __launch_bounds__(256) void attn_kernel(
    const float* __restrict__ proj, const float* __restrict__ pp,
    const float* __restrict__ Wscore, const float* __restrict__ bH,
    float* __restrict__ ctx)
{
  __shared__ float s_pp[H_];
  __shared__ float s_ws[H_];
  __shared__ float s_e[T_];
  __shared__ float s_red[8];
  const int tid = threadIdx.x;
  const int b   = blockIdx.x;
  for (int i=tid;i<H_;i+=256){ s_pp[i]=pp[(size_t)b*H_+i]; s_ws[i]=Wscore[i]; }
  __syncthreads();
  const int wave = tid>>6, lane = tid&63;
  for (int t=wave; t<T_; t+=4){
    const float* pr = proj + ((size_t)b*T_ + t)*H_;
    float acc = 0.f;
#pragma unroll
    for (int i=0;i<8;i++){
      int hh = lane + 64*i;
      acc += s_ws[hh]*tanhf(pr[hh]+s_pp[hh]);
    }
#pragma unroll
    for (int off=32; off>0; off>>=1) acc += __shfl_down(acc, off);
    if (lane==0) s_e[t] = acc;
  }
  __syncthreads();
  // softmax over s_e[0..127]
  float v = (tid < T_) ? s_e[tid] : -INFINITY;
  float m = v;
#pragma unroll
  for (int off=32; off>0; off>>=1) m = fmaxf(m, __shfl_down(m, off));
  if (lane==0) s_red[wave] = m;
  __syncthreads();
  m = fmaxf(fmaxf(s_red[0],s_red[1]), fmaxf(s_red[2],s_red[3]));
  float p = (tid < T_) ? expf(v - m) : 0.f;
  float sum = p;
#pragma unroll
  for (int off=32; off>0; off>>=1) sum += __shfl_down(sum, off);
  if (lane==0) s_red[4+wave] = sum;
  __syncthreads();
  const float denom = s_red[4]+s_red[5]+s_red[6]+s_red[7];
  if (tid < T_) s_e[tid] = p/denom;
  __syncthreads();
  // context
  float a0=0.f, a1=0.f;
  for (int t=0;t<T_;t++){
    const float al = s_e[t];
    const float* hr = bH + ((size_t)b*T_+t)*D_;
    a0 += al*hr[tid];
    a1 += al*hr[tid+256];
  }
  ctx[(size_t)b*D_ + tid]       = a0;
  ctx[(size_t)b*D_ + 256 + tid] = a1;
}

// ---------------------------------------------------------------------------
// LSTM pointwise: token one-hots folded in as W_ih column adds.
// ---------------------------------------------------------------------------
__global__ __launch_bounds__(256) void lstm_pointwise(
    const float* __restrict__ gates, const float* __restrict__ Wih,
    const int* __restrict__ midtok, const int* __restrict__ bottok,
    float* __restrict__ c, float* __restrict__ h, float* __restrict__ hid_s,
    int s)
{
  const int idx = blockIdx.x*256 + threadIdx.x;   // 0 .. B*H-1
  const int b = idx >> 9;
  const int j = idx & 511;
  const int mt = midtok[b*26 + s];
  const int bt = bottok[b*26 + s];
  const int cm = D_ + mt;
  const int cb = D_ + MID_ + bt;
  float ig = gates[(size_t)b*2048 + j       ] + Wih[(size_t)(j       )*XL_ + cm] + Wih[(size_t)(j       )*XL_ + cb];
  float fg = gates[(size_t)b*2048 + 512  + j] + Wih[(size_t)(512 + j )*XL_ + cm] + Wih[(size_t)(512 + j )*XL_ + cb];
  float gg = gates[(size_t)b*2048 + 1024 + j] + Wih[(size_t)(1024+ j )*XL_ + cm] + Wih[(size_t)(1024+ j )*XL_ + cb];
  float og = gates[(size_t)b*2048 + 1536 + j] + Wih[(size_t)(1536+ j )*XL_ + cm] + Wih[(size_t)(1536+ j )*XL_ + cb];
  ig = sigmoidf_(ig);
  fg = sigmoidf_(fg);
  gg = tanhf(gg);
  og = sigmoidf_(og);
  const float cn = fg*c[idx] + ig*gg;
  const float hn = og*tanhf(cn);
  c[idx] = cn;
  h[idx] = hn;
  hid_s[idx] = hn;
}

// ---------------------------------------------------------------------------
// Generator: out[b,s,c] = hid[s,b,:] . W_gen[c,:] + b_gen[c]
// ---------------------------------------------------------------------------
__global__ __launch_bounds__(64) void gen_kernel(
    const float* __restrict__ hid, const float* __restrict__ Wg,
    const float* __restrict__ bg, float* __restrict__ out)
{
  __shared__ float s_h[H_];
  const int r = blockIdx.x;            // r = s*B + b
  const int s = r / B_, b = r % B_;
  const int lane = threadIdx.x;
  const float* hrow = hid + (size_t)r*H_;
  for (int i=lane;i<H_;i+=64) s_h[i]=hrow[i];
  __syncthreads();
  if (lane < MID_){
    const float* wr = Wg + (size_t)lane*H_;
    float acc = bg[lane];
    for (int k=0;k<H_;k+=4){
      acc += s_h[k]*wr[k] + s_h[k+1]*wr[k+1] + s_h[k+2]*wr[k+2] + s_h[k+3]*wr[k+3];
    }
    out[((size_t)b*S_ + s)*MID_ + lane] = acc;
  }
}

extern "C" void kernel_launch(void* const* d_in, const int* in_sizes, int n_in,
                              void* d_out, int out_size, void* d_ws, size_t ws_size,
                              hipStream_t stream) {
  const float* bH   = (const float*)d_in[0];
  const int*   midt = (const int*)  d_in[1];
  const int*   bott = (const int*)  d_in[2];
  const float* Wi2h = (const float*)d_in[3];
  const float* Wh2h = (const float*)d_in[4];
  const float* bh2h = (const float*)d_in[5];
  const float* Wsc  = (const float*)d_in[6];
  const float* Wih  = (const float*)d_in[7];
  const float* Whh  = (const float*)d_in[8];
  const float* bih  = (const float*)d_in[9];
  const float* bhh  = (const float*)d_in[10];
  const float* Wgen = (const float*)d_in[11];
  const float* bgen = (const float*)d_in[12];
  float* out = (float*)d_out;

  float* ws    = (float*)d_ws;
  float* proj  = ws;                                   // B*T*H
  float* pp    = proj  + (size_t)B_*T_*H_;             // B*H
  float* ctx   = pp    + (size_t)B_*H_;                // B*D
  float* gates = ctx   + (size_t)B_*D_;                // B*4H
  float* h     = gates + (size_t)B_*4*H_;              // B*H
  float* c     = h     + (size_t)B_*H_;                // B*H
  float* hid   = c     + (size_t)B_*H_;                // S*B*H

  hipMemsetAsync(h, 0, (size_t)B_*H_*sizeof(float), stream);
  hipMemsetAsync(c, 0, (size_t)B_*H_*sizeof(float), stream);

  // proj = batch_H @ W_i2h^T : M=65536, N=512, K=512
  sgemm_nt<128,128,32,8,8><<<dim3(512/128, 65536/128), 256, 0, stream>>>(
      bH,512, Wi2h,512, nullptr,0, nullptr,0, nullptr,nullptr,
      proj, 65536,512,512, 1);

  for (int s=0; s<S_; ++s){
    // pp = h @ W_h2h^T + b_h2h
    sgemm_nt<32,32,32,2,2><<<dim3(512/32, 512/32), 256, 0, stream>>>(
        h,512, Wh2h,512, nullptr,0, nullptr,0, bh2h,nullptr,
        pp, 512,512,512, 1);
    // e, softmax, context (fused)
    attn_kernel<<<B_, 256, 0, stream>>>(proj, pp, Wsc, bH, ctx);
    // gates = ctx @ W_ih[:, :512]^T + h @ W_hh^T + b_ih + b_hh
    sgemm_nt<64,64,32,4,4><<<dim3(2048/64, 512/64), 256, 0, stream>>>(
        ctx,512, Wih,XL_, h,512, Whh,512, bih,bhh,
        gates, 512,2048,512, 2);
    // LSTM update (+ one-hot column adds), store h into hiddens[s]
    lstm_pointwise<<<(B_*H_)/256, 256, 0, stream>>>(
        gates, Wih, midt, bott, c, h, hid + (size_t)s*B_*H_, s);
  }

  gen_kernel<<<S_*B_, 64, 0, stream>>>(hid, Wgen, bgen, out);
}

// Round 2
// 4009.575 us; speedup vs baseline: 1.6647x; 1.6647x over previous
//
#include <hip/hip_runtime.h>
#include <hip/hip_bf16.h>
#include <cstdint>
#include <cstddef>

#define B_   512
#define T_   128
#define D_   512
#define H_   512
#define MID_ 38
#define BOT_ 38
#define S_   26
#define XL_  588   // D + MID + BOT = W_ih row length

typedef unsigned short u16;
typedef __attribute__((ext_vector_type(8))) short bf16x8v;
typedef __attribute__((ext_vector_type(8))) unsigned short u16x8;
typedef __attribute__((ext_vector_type(4))) float f32x4v;

__device__ __forceinline__ float sigmoidf_(float x){ return 1.0f/(1.0f+expf(-x)); }

__device__ __forceinline__ u16 f2bf_rn(float f){
  unsigned u = __float_as_uint(f);
  return (u16)((u + 0x7fffu + ((u>>16)&1u)) >> 16);
}
__device__ __forceinline__ float bf2f(u16 v){ return __uint_as_float(((unsigned)v)<<16); }
__device__ __forceinline__ u16 f2bf_lo(float f){
  u16 hi = f2bf_rn(f);
  return f2bf_rn(f - bf2f(hi));
}
__device__ __forceinline__ u16x8 cvt8(float4 a, float4 b, bool lo){
  float f[8] = {a.x,a.y,a.z,a.w,b.x,b.y,b.z,b.w};
  u16x8 v;
#pragma unroll
  for (int j=0;j<8;j++) v[j] = lo ? f2bf_lo(f[j]) : f2bf_rn(f[j]);
  return v;
}

// ---------------------------------------------------------------------------
// bf16 MFMA GEMM, K=512 fixed, NT layout (both A and B given row-major with K
// contiguous):  C[m,n] = sum_k A[m,k]*B[n,k].
// npass=1: plain bf16 (round-to-nearest).  npass=3: bf16x2 split
// (A_hi*B_hi + A_hi*B_lo + A_lo*B_hi) ~= fp32 precision.
// B operand region-split at column N1 (B0 rows for n<N1, B1 rows for n>=N1).
// OUTBF: write bf16 (via LDS bounce for coalescing); else fp32 with optional
// Cin accumulate and bias.
// Structure: m97-style single-buffer LDS, reg-staged with on-the-fly convert,
// 2x2 waves of (BM/2 x BN/2), 16x16x32 MFMA frags.
// ---------------------------------------------------------------------------
template<int BM,int BN,bool OUTBF>
__global__ __launch_bounds__(256) void gemm_bf16x(
    const float* __restrict__ A, int lda,
    const float* __restrict__ B0, int ldb0, int N1,
    const float* __restrict__ B1, int ldb1,
    const float* __restrict__ Cin, int ldcin,
    const float* __restrict__ bias,
    float* __restrict__ Cout, u16* __restrict__ CoutB, int ldc,
    int npass)
{
  extern __shared__ char smem[];
  short* As = (short*)smem;
  short* Bs = As + BM*32;
  const int tid = threadIdx.x;
  const int bm = blockIdx.y*BM, bn = blockIdx.x*BN;
  const int w = tid>>6, lane = tid&63;
  constexpr int WM=BM/2, WN=BN/2, FM=WM/16, FN=WN/16;
  const int wr = w>>1, wc = w&1;
  const float* Bp; int ldb, bnl;
  if (bn < N1){ Bp=B0; ldb=ldb0; bnl=bn; } else { Bp=B1; ldb=ldb1; bnl=bn-N1; }

  constexpr int LA = BM/64, LB = BN/64;   // 16B LDS chunks per thread
  const int nIter = npass*16;             // K=512, BK=32 -> 16 steps/pass

  f32x4v acc[FM][FN];
#pragma unroll
  for (int i=0;i<FM;i++)
#pragma unroll
    for (int j=0;j<FN;j++) acc[i][j] = (f32x4v){0.f,0.f,0.f,0.f};

  float4 ra[LA][2], rb[LB][2];
  auto loadTiles = [&](int it){
    const int kk = (it & 15) << 5;
#pragma unroll
    for (int L=0; L<LA; L++){
      int t = L*256 + tid, row = t>>2, c8 = (t&3)*8;
      const float* p = A + (size_t)(bm+row)*lda + kk + c8;
      ra[L][0] = *(const float4*)p;
      ra[L][1] = *(const float4*)(p+4);
    }
#pragma unroll
    for (int L=0; L<LB; L++){
      int t = L*256 + tid, row = t>>2, c8 = (t&3)*8;
      const float* p = Bp + (size_t)(bnl+row)*ldb + kk + c8;
      rb[L][0] = *(const float4*)p;
      rb[L][1] = *(const float4*)(p+4);
    }
  };
  loadTiles(0);

  for (int it=0; it<nIter; ++it){
    const int pass = it >> 4;
    const bool aLo = (pass==2), bLo = (pass==1);
    __syncthreads();
#pragma unroll
    for (int L=0; L<LA; L++){ int t=L*256+tid; *(u16x8*)&As[t*8] = cvt8(ra[L][0],ra[L][1],aLo); }
#pragma unroll
    for (int L=0; L<LB; L++){ int t=L*256+tid; *(u16x8*)&Bs[t*8] = cvt8(rb[L][0],rb[L][1],bLo); }
    if (it+1 < nIter) loadTiles(it+1);
    __syncthreads();
    bf16x8v af[FM], bfr[FN];
    const int koff = (lane>>4)*8, mrow = lane&15;
#pragma unroll
    for (int i=0;i<FM;i++) af[i]  = *(const bf16x8v*)&As[(wr*WM+i*16+mrow)*32 + koff];
#pragma unroll
    for (int j=0;j<FN;j++) bfr[j] = *(const bf16x8v*)&Bs[(wc*WN+j*16+mrow)*32 + koff];
#pragma unroll
    for (int i=0;i<FM;i++)
#pragma unroll
      for (int j=0;j<FN;j++)
        acc[i][j] = __builtin_amdgcn_mfma_f32_16x16x32_bf16(af[i], bfr[j], acc[i][j], 0,0,0);
  }

  // Epilogue.  C/D layout (m89-verified): col = lane&15, row = (lane>>4)*4 + r.
  const int r0 = (lane>>4)*4, cn = lane&15;
  if constexpr (OUTBF){
    __syncthreads();
    u16* Ts = (u16*)smem;   // [BM][BN] bf16 bounce tile
#pragma unroll
    for (int i=0;i<FM;i++)
#pragma unroll
      for (int j=0;j<FN;j++)
#pragma unroll
        for (int r=0;r<4;r++)
          Ts[(wr*WM+i*16+r0+r)*BN + wc*WN+j*16+cn] = f2bf_rn(acc[i][j][r]);
    __syncthreads();
#pragma unroll
    for (int q=0;q<(BM*BN/8)/256;q++){
      int idx = q*256 + tid;
      int row = idx/(BN/8), c8 = (idx%(BN/8))*8;
      *(float4*)&CoutB[(size_t)(bm+row)*ldc + bn + c8] = *(const float4*)&Ts[row*BN + c8];
    }
  } else {
#pragma unroll
    for (int i=0;i<FM;i++)
#pragma unroll
      for (int j=0;j<FN;j++)
#pragma unroll
        for (int r=0;r<4;r++){
          int row = bm + wr*WM + i*16 + r0 + r;
          int col = bn + wc*WN + j*16 + cn;
          float v = acc[i][j][r];
          if (Cin)  v += Cin[(size_t)row*ldcin + col];
          if (bias) v += bias[col];
          Cout[(size_t)row*ldc + col] = v;
        }
  }
}

// ---------------------------------------------------------------------------
// Fused attention: e[t] = sum_h Ws[h]*tanh(proj_bf16[b,t,h]+pp[b,h]);
// softmax over t; context[b,d] = sum_t alpha[t]*batch_H[b,t,d] (fp32 exact).
// pp comes from combo[:, 0:512] (ld 2560).
// ---------------------------------------------------------------------------
__global__ __launch_bounds__(256) void attn_kernel(
    const u16* __restrict__ projb, const float* __restrict__ combo,
    const float* __restrict__ Wscore, const float* __restrict__ bH,
    float* __restrict__ ctx)
{
  __shared__ float s_e[T_];
  __shared__ float s_red[8];
  const int tid=threadIdx.x, b=blockIdx.x, wave=tid>>6, lane=tid&63;
  // per-lane pp / Ws registers for h = lane*8 .. lane*8+7
  float pv[8], wv[8];
  {
    const float* pprow = combo + (size_t)b*2560;
    float4 p0=*(const float4*)&pprow[lane*8], p1=*(const float4*)&pprow[lane*8+4];
    float4 w0=*(const float4*)&Wscore[lane*8], w1=*(const float4*)&Wscore[lane*8+4];
    pv[0]=p0.x;pv[1]=p0.y;pv[2]=p0.z;pv[3]=p0.w;pv[4]=p1.x;pv[5]=p1.y;pv[6]=p1.z;pv[7]=p1.w;
    wv[0]=w0.x;wv[1]=w0.y;wv[2]=w0.z;wv[3]=w0.w;wv[4]=w1.x;wv[5]=w1.y;wv[6]=w1.z;wv[7]=w1.w;
  }
  for (int t=wave; t<T_; t+=4){
    u16x8 vv = *(const u16x8*)(projb + ((size_t)b*T_+t)*H_ + lane*8);
    float acc = 0.f;
#pragma unroll
    for (int j=0;j<8;j++) acc += wv[j]*tanhf(bf2f(vv[j]) + pv[j]);
#pragma unroll
    for (int o=32;o>0;o>>=1) acc += __shfl_down(acc,o);
    if (lane==0) s_e[t] = acc;
  }
  __syncthreads();
  // softmax over s_e[0..127]
  float v = (tid < T_) ? s_e[tid] : -INFINITY;
  float m = v;
#pragma unroll
  for (int o=32;o>0;o>>=1) m = fmaxf(m, __shfl_down(m,o));
  if (lane==0) s_red[wave] = m;
  __syncthreads();
  m = fmaxf(fmaxf(s_red[0],s_red[1]), fmaxf(s_red[2],s_red[3]));
  float p = (tid < T_) ? expf(v - m) : 0.f;
  float sum = p;
#pragma unroll
  for (int o=32;o>0;o>>=1) sum += __shfl_down(sum,o);
  if (lane==0) s_red[4+wave] = sum;
  __syncthreads();
  const float denom = s_red[4]+s_red[5]+s_red[6]+s_red[7];
  if (tid < T_) s_e[tid] = p/denom;
  __syncthreads();
  // context (fp32 exact)
  float a0=0.f, a1=0.f;
  for (int t=0;t<T_;t++){
    const float al = s_e[t];
    const float* hr = bH + ((size_t)b*T_+t)*D_;
    a0 += al*hr[tid];
    a1 += al*hr[tid+256];
  }
  ctx[(size_t)b*D_ + tid]       = a0;
  ctx[(size_t)b*D_ + 256 + tid] = a1;
}

// ---------------------------------------------------------------------------
// LSTM pointwise: token one-hots folded in as W_ih column adds.
// ---------------------------------------------------------------------------
__global__ __launch_bounds__(256) void lstm_pointwise(
    const float* __restrict__ gates, const float* __restrict__ Wih,
    const int* __restrict__ midtok, const int* __restrict__ bottok,
    float* __restrict__ c, float* __restrict__ h, float* __restrict__ hid_s,
    int s)
{
  const int idx = blockIdx.x*256 + threadIdx.x;   // 0 .. B*H-1
  const int b = idx >> 9;
  const int j = idx & 511;
  const int mt = midtok[b*26 + s];
  const int bt = bottok[b*26 + s];
  const int cm = D_ + mt;
  const int cb = D_ + MID_ + bt;
  float ig = gates[(size_t)b*2048 + j       ] + Wih[(size_t)(j       )*XL_ + cm] + Wih[(size_t)(j       )*XL_ + cb];
  float fg = gates[(size_t)b*2048 + 512  + j] + Wih[(size_t)(512 + j )*XL_ + cm] + Wih[(size_t)(512 + j )*XL_ + cb];
  float gg = gates[(size_t)b*2048 + 1024 + j] + Wih[(size_t)(1024+ j )*XL_ + cm] + Wih[(size_t)(1024+ j )*XL_ + cb];
  float og = gates[(size_t)b*2048 + 1536 + j] + Wih[(size_t)(1536+ j )*XL_ + cm] + Wih[(size_t)(1536+ j )*XL_ + cb];
  ig = sigmoidf_(ig);
  fg = sigmoidf_(fg);
  gg = tanhf(gg);
  og = sigmoidf_(og);
  const float cn = fg*c[idx] + ig*gg;
  const float hn = og*tanhf(cn);
  c[idx] = cn;
  h[idx] = hn;
  hid_s[idx] = hn;
}

// ---------------------------------------------------------------------------
// bias combine: bcomb[0:512] = b_h2h; bcomb[512+j] = b_ih[j] + b_hh[j]
// ---------------------------------------------------------------------------
__global__ __launch_bounds__(256) void bcomb_kernel(
    const float* __restrict__ bh2h, const float* __restrict__ bih,
    const float* __restrict__ bhh, float* __restrict__ o)
{
  int i = blockIdx.x*256 + threadIdx.x;
  if (i < 512) o[i] = bh2h[i];
  else if (i < 2560) o[i] = bih[i-512] + bhh[i-512];
}

// ---------------------------------------------------------------------------
// Generator: out[b,s,c] = hid[s,b,:] . W_gen[c,:] + b_gen[c]
// ---------------------------------------------------------------------------
__global__ __launch_bounds__(64) void gen_kernel(
    const float* __restrict__ hid, const float* __restrict__ Wg,
    const float* __restrict__ bg, float* __restrict__ out)
{
  __shared__ float s_h[H_];
  const int r = blockIdx.x;            // r = s*B + b
  const int s = r / B_, b = r % B_;
  const int lane = threadIdx.x;
  const float* hrow = hid + (size_t)r*H_;
  for (int i=lane;i<H_;i+=64) s_h[i]=hrow[i];
  __syncthreads();
  if (lane < MID_){
    const float* wr = Wg + (size_t)lane*H_;
    float acc = bg[lane];
    for (int k=0;k<H_;k+=4){
      acc += s_h[k]*wr[k] + s_h[k+1]*wr[k+1] + s_h[k+2]*wr[k+2] + s_h[k+3]*wr[k+3];
    }
    out[((size_t)b*S_ + s)*MID_ + lane] = acc;
  }
}

extern "C" void kernel_launch(void* const* d_in, const int* in_sizes, int n_in,
                              void* d_out, int out_size, void* d_ws, size_t ws_size,
                              hipStream_t stream) {
  const float* bH   = (const float*)d_in[0];
  const int*   midt = (const int*)  d_in[1];
  const int*   bott = (const int*)  d_in[2];
  const float* Wi2h = (const float*)d_in[3];
  const float* Wh2h = (const float*)d_in[4];
  const float* bh2h = (const float*)d_in[5];
  const float* Wsc  = (const float*)d_in[6];
  const float* Wih  = (const float*)d_in[7];
  const float* Whh  = (const float*)d_in[8];
  const float* bih  = (const float*)d_in[9];
  const float* bhh  = (const float*)d_in[10];
  const float* Wgen = (const float*)d_in[11];
  const float* bgen = (const float*)d_in[12];
  float* out = (float*)d_out;

  char* wp = (char*)d_ws;
  u16*   projb = (u16*)wp;   wp += (size_t)B_*T_*H_*2;     // 67.1 MB bf16 proj
  float* combo = (float*)wp; wp += (size_t)B_*2560*4;      // pp | gatesH
  float* gates = (float*)wp; wp += (size_t)B_*2048*4;
  float* ctx   = (float*)wp; wp += (size_t)B_*512*4;
  float* h     = (float*)wp; wp += (size_t)B_*H_*4;
  float* c     = (float*)wp; wp += (size_t)B_*H_*4;
  float* bcomb = (float*)wp; wp += (size_t)2560*4;
  float* hid   = (float*)wp; wp += (size_t)S_*B_*H_*4;
  if ((size_t)(wp - (char*)d_ws) > ws_size) return;  // fail loudly (poisoned out)

  hipMemsetAsync(h, 0, (size_t)B_*H_*sizeof(float), stream);
  hipMemsetAsync(c, 0, (size_t)B_*H_*sizeof(float), stream);
  bcomb_kernel<<<10, 256, 0, stream>>>(bh2h, bih, bhh, bcomb);

  // proj = bf16( batch_H @ W_i2h^T ) : M=65536, N=512, K=512, 1-pass bf16
  gemm_bf16x<128,128,true><<<dim3(4,512), 256, 32768, stream>>>(
      bH,512, Wi2h,512, 1<<30, nullptr,0,
      nullptr,0, nullptr, nullptr, projb, 512, 1);

  for (int s=0; s<S_; ++s){
    // combo = [h@W_h2h^T + b_h2h | h@W_hh^T + b_ih + b_hh]  (bf16x2, 3 passes)
    gemm_bf16x<64,64,false><<<dim3(2560/64, 512/64), 256, 8192, stream>>>(
        h,512, Wh2h,512, 512, Whh,512,
        nullptr,0, bcomb, combo, nullptr, 2560, 3);
    // attention (reads bf16 proj + fp32 bH)
    attn_kernel<<<B_, 256, 0, stream>>>(projb, combo, Wsc, bH, ctx);
    // gates = combo[:,512:] + ctx @ W_ih[:, :512]^T   (bf16x2, 3 passes)
    gemm_bf16x<64,64,false><<<dim3(2048/64, 512/64), 256, 8192, stream>>>(
        ctx,512, Wih,XL_, 1<<30, nullptr,0,
        combo+512, 2560, nullptr, gates, nullptr, 2048, 3);
    // LSTM update (+ one-hot column adds), store h into hiddens[s]
    lstm_pointwise<<<(B_*H_)/256, 256, 0, stream>>>(
        gates, Wih, midt, bott, c, h, hid + (size_t)s*B_*H_, s);
  }

  gen_kernel<<<S_*B_, 64, 0, stream>>>(hid, Wgen, bgen, out);
}

// Round 3
// 2794.760 us; speedup vs baseline: 2.3883x; 1.4347x over previous
//
#include <hip/hip_runtime.h>
#include <hip/hip_bf16.h>
#include <cstdint>
#include <cstddef>

#define B_   512
#define T_   128
#define D_   512
#define H_   512
#define MID_ 38
#define BOT_ 38
#define S_   26
#define XL_  588   // D + MID + BOT = W_ih row length

typedef unsigned short u16;
typedef __attribute__((ext_vector_type(8))) short bf16x8v;
typedef __attribute__((ext_vector_type(8))) unsigned short u16x8;
typedef __attribute__((ext_vector_type(4))) float f32x4v;

__device__ __forceinline__ float sigmoidf_(float x){ return 1.0f/(1.0f+expf(-x)); }
__device__ __forceinline__ u16 f2bf_rn(float f){
  unsigned u = __float_as_uint(f);
  return (u16)((u + 0x7fffu + ((u>>16)&1u)) >> 16);
}
__device__ __forceinline__ float bf2f(u16 v){ return __uint_as_float(((unsigned)v)<<16); }

// ---------------------------------------------------------------------------
// fp32 -> bf16 hi/lo plane decomposition (lo nullable). Takes first 512 cols
// of src rows; rows >= `rows` are zero-padded up to padrows.
// ---------------------------------------------------------------------------
__global__ __launch_bounds__(256) void cvt_plane(
    const float* __restrict__ src, int ld, int rows, int padrows,
    u16* __restrict__ hi, u16* __restrict__ lo)
{
  const int n4 = padrows*128;
  for (int i = blockIdx.x*256 + threadIdx.x; i < n4; i += gridDim.x*256){
    const int row = i >> 7, c4 = (i & 127)*4;
    float4 v = make_float4(0.f,0.f,0.f,0.f);
    if (row < rows) v = *(const float4*)&src[(size_t)row*ld + c4];
    ushort4 h;
    h.x=f2bf_rn(v.x); h.y=f2bf_rn(v.y); h.z=f2bf_rn(v.z); h.w=f2bf_rn(v.w);
    *(ushort4*)&hi[(size_t)row*512 + c4] = h;
    if (lo){
      ushort4 l;
      l.x=f2bf_rn(v.x-bf2f(h.x)); l.y=f2bf_rn(v.y-bf2f(h.y));
      l.z=f2bf_rn(v.z-bf2f(h.z)); l.w=f2bf_rn(v.w-bf2f(h.w));
      *(ushort4*)&lo[(size_t)row*512 + c4] = l;
    }
  }
}

// token-column tables, transposed for coalesced pointwise reads
__global__ __launch_bounds__(256) void build_tokT(
    const float* __restrict__ Wih, float* __restrict__ WmT, float* __restrict__ WbT)
{
  int i = blockIdx.x*256 + threadIdx.x;   // over 38*2048
  if (i < MID_*2048){
    int c = i >> 11, j = i & 2047;
    WmT[i] = Wih[(size_t)j*XL_ + 512 + c];
    WbT[i] = Wih[(size_t)j*XL_ + 512 + MID_ + c];
  }
}

// ---------------------------------------------------------------------------
// Pure-bf16 MFMA GEMM, K=512, NT.  npass=1: hi*hi.  npass=3: bf16x2 split
// (hi*hi + hi*lo + lo*hi).  MODE 0: fp32 out (+Cin,+bias).  MODE 1: bf16 out
// via LDS bounce.  MODE 2: generator out (m -> (s,b) permuted, n<38, +bias2).
// ---------------------------------------------------------------------------
template<int BM,int BN,int MODE>
__global__ __launch_bounds__(256) void gemm_bf(
    const u16* __restrict__ Ah, const u16* __restrict__ Al, int lda,
    const u16* __restrict__ Bh, const u16* __restrict__ Bl, int ldb,
    const float* __restrict__ Cin, int ldcin, const float* __restrict__ bias,
    float* __restrict__ Cout, u16* __restrict__ CoutB, int ldc,
    const float* __restrict__ bias2, int npass)
{
  extern __shared__ char smem[];
  constexpr int STR = 40;                    // padded LDS stride (shorts)
  short* As = (short*)smem;                  // [BM][STR]
  short* Bs = As + BM*STR;                   // [BN][STR]
  const int tid=threadIdx.x, bm=blockIdx.y*BM, bn=blockIdx.x*BN;
  const int w=tid>>6, lane=tid&63, wr=w>>1, wc=w&1;
  constexpr int WM=BM/2, WN=BN/2, FM=WM/16, FN=WN/16;
  constexpr int LA=BM/64, LB=BN/64;          // 16B chunks per thread
  const int nIter = npass*16;

  f32x4v acc[FM][FN];
#pragma unroll
  for (int i=0;i<FM;i++)
#pragma unroll
    for (int j=0;j<FN;j++) acc[i][j] = (f32x4v){0.f,0.f,0.f,0.f};

  u16x8 ra[LA], rb[LB];
  auto load = [&](int it){
    const int pass = it>>4, kk = (it&15)<<5;
    const u16* Ap = (pass==2)?Al:Ah;
    const u16* Bp = (pass==1)?Bl:Bh;
#pragma unroll
    for (int L=0; L<LA; L++){
      int t=L*256+tid, row=t>>2, c=(t&3)*8;
      ra[L] = *(const u16x8*)&Ap[(size_t)(bm+row)*lda + kk + c];
    }
#pragma unroll
    for (int L=0; L<LB; L++){
      int t=L*256+tid, row=t>>2, c=(t&3)*8;
      rb[L] = *(const u16x8*)&Bp[(size_t)(bn+row)*ldb + kk + c];
    }
  };
  load(0);

  for (int it=0; it<nIter; ++it){
    __syncthreads();
#pragma unroll
    for (int L=0; L<LA; L++){ int t=L*256+tid; *(u16x8*)&As[(t>>2)*STR+(t&3)*8] = ra[L]; }
#pragma unroll
    for (int L=0; L<LB; L++){ int t=L*256+tid; *(u16x8*)&Bs[(t>>2)*STR+(t&3)*8] = rb[L]; }
    if (it+1 < nIter) load(it+1);
    __syncthreads();
    bf16x8v af[FM], bfr[FN];
    const int koff = (lane>>4)*8, mrow = lane&15;
#pragma unroll
    for (int i=0;i<FM;i++) af[i]  = *(const bf16x8v*)&As[(wr*WM+i*16+mrow)*STR + koff];
#pragma unroll
    for (int j=0;j<FN;j++) bfr[j] = *(const bf16x8v*)&Bs[(wc*WN+j*16+mrow)*STR + koff];
#pragma unroll
    for (int i=0;i<FM;i++)
#pragma unroll
      for (int j=0;j<FN;j++)
        acc[i][j] = __builtin_amdgcn_mfma_f32_16x16x32_bf16(af[i], bfr[j], acc[i][j], 0,0,0);
  }

  // C/D layout (m89): col = lane&15, row = (lane>>4)*4 + r.
  const int r0 = (lane>>4)*4, cn = lane&15;
  if constexpr (MODE==1){
    __syncthreads();
    u16* Ts = (u16*)smem;   // [BM][BN] bf16 bounce
#pragma unroll
    for (int i=0;i<FM;i++)
#pragma unroll
      for (int j=0;j<FN;j++)
#pragma unroll
        for (int r=0;r<4;r++)
          Ts[(wr*WM+i*16+r0+r)*BN + wc*WN+j*16+cn] = f2bf_rn(acc[i][j][r]);
    __syncthreads();
#pragma unroll
    for (int q=0;q<(BM*BN/8)/256;q++){
      int idx = q*256 + tid;
      int row = idx/(BN/8), c8 = (idx%(BN/8))*8;
      *(float4*)&CoutB[(size_t)(bm+row)*ldc + bn + c8] = *(const float4*)&Ts[row*BN + c8];
    }
  } else if constexpr (MODE==2){
#pragma unroll
    for (int i=0;i<FM;i++)
#pragma unroll
      for (int j=0;j<FN;j++)
#pragma unroll
        for (int r=0;r<4;r++){
          int m = bm + wr*WM + i*16 + r0 + r;       // m = s*512 + b
          int n = bn + wc*WN + j*16 + cn;
          if (n < MID_){
            int s = m >> 9, b = m & 511;
            Cout[((size_t)b*S_ + s)*MID_ + n] = acc[i][j][r] + bias2[n];
          }
        }
  } else {
#pragma unroll
    for (int i=0;i<FM;i++)
#pragma unroll
      for (int j=0;j<FN;j++)
#pragma unroll
        for (int r=0;r<4;r++){
          int row = bm + wr*WM + i*16 + r0 + r;
          int col = bn + wc*WN + j*16 + cn;
          float v = acc[i][j][r];
          if (Cin)  v += Cin[(size_t)row*ldcin + col];
          if (bias) v += bias[col];
          Cout[(size_t)row*ldc + col] = v;
        }
  }
}

// ---------------------------------------------------------------------------
// Fused attention: e[t] = sum_h Ws[h]*tanh(projb[b,t,h]+pp[b,h]); softmax;
// context[b,d] = sum_t alpha[t]*bH[b,t,d] (fp32 exact) -> bf16 hi/lo planes.
// ---------------------------------------------------------------------------
__global__ __launch_bounds__(256) void attn_kernel(
    const u16* __restrict__ projb, const float* __restrict__ combo,
    const float* __restrict__ Wscore, const float* __restrict__ bH,
    u16* __restrict__ ctx_hi, u16* __restrict__ ctx_lo)
{
  __shared__ float s_e[T_];
  __shared__ float s_red[8];
  __shared__ float s_part[4][D_];
  const int tid=threadIdx.x, b=blockIdx.x, wave=tid>>6, lane=tid&63;
  float pv[8], wv[8];
  {
    const float* pprow = combo + (size_t)b*2560;
    float4 p0=*(const float4*)&pprow[lane*8], p1=*(const float4*)&pprow[lane*8+4];
    float4 w0=*(const float4*)&Wscore[lane*8], w1=*(const float4*)&Wscore[lane*8+4];
    pv[0]=p0.x;pv[1]=p0.y;pv[2]=p0.z;pv[3]=p0.w;pv[4]=p1.x;pv[5]=p1.y;pv[6]=p1.z;pv[7]=p1.w;
    wv[0]=w0.x;wv[1]=w0.y;wv[2]=w0.z;wv[3]=w0.w;wv[4]=w1.x;wv[5]=w1.y;wv[6]=w1.z;wv[7]=w1.w;
  }
  for (int t=wave; t<T_; t+=4){
    u16x8 vv = *(const u16x8*)(projb + ((size_t)b*T_+t)*H_ + lane*8);
    float acc = 0.f;
#pragma unroll
    for (int j=0;j<8;j++) acc += wv[j]*tanhf(bf2f(vv[j]) + pv[j]);
#pragma unroll
    for (int o=32;o>0;o>>=1) acc += __shfl_down(acc,o);
    if (lane==0) s_e[t] = acc;
  }
  __syncthreads();
  float v = (tid < T_) ? s_e[tid] : -INFINITY;
  float m = v;
#pragma unroll
  for (int o=32;o>0;o>>=1) m = fmaxf(m, __shfl_down(m,o));
  if (lane==0) s_red[wave] = m;
  __syncthreads();
  m = fmaxf(fmaxf(s_red[0],s_red[1]), fmaxf(s_red[2],s_red[3]));
  float p = (tid < T_) ? expf(v - m) : 0.f;
  float sum = p;
#pragma unroll
  for (int o=32;o>0;o>>=1) sum += __shfl_down(sum,o);
  if (lane==0) s_red[4+wave] = sum;
  __syncthreads();
  const float denom = s_red[4]+s_red[5]+s_red[6]+s_red[7];
  if (tid < T_) s_e[tid] = p/denom;
  __syncthreads();
  // context: wave w covers t in [32w, 32w+32), lane covers d = lane*8..+7
  const int d0 = lane*8;
  float a[8] = {0,0,0,0,0,0,0,0};
  for (int t=wave*32; t<wave*32+32; ++t){
    const float al = s_e[t];
    const float* hr = bH + ((size_t)b*T_+t)*D_ + d0;
    float4 h0=*(const float4*)hr, h1=*(const float4*)(hr+4);
    a[0]+=al*h0.x; a[1]+=al*h0.y; a[2]+=al*h0.z; a[3]+=al*h0.w;
    a[4]+=al*h1.x; a[5]+=al*h1.y; a[6]+=al*h1.z; a[7]+=al*h1.w;
  }
  *(float4*)&s_part[wave][d0]   = make_float4(a[0],a[1],a[2],a[3]);
  *(float4*)&s_part[wave][d0+4] = make_float4(a[4],a[5],a[6],a[7]);
  __syncthreads();
  const int d = tid*2;
  float v0 = s_part[0][d]  +s_part[1][d]  +s_part[2][d]  +s_part[3][d];
  float v1 = s_part[0][d+1]+s_part[1][d+1]+s_part[2][d+1]+s_part[3][d+1];
  u16 h0=f2bf_rn(v0), l0=f2bf_rn(v0-bf2f(h0));
  u16 h1=f2bf_rn(v1), l1=f2bf_rn(v1-bf2f(h1));
  ushort2 hh; hh.x=h0; hh.y=h1;
  ushort2 ll; ll.x=l0; ll.y=l1;
  *(ushort2*)&ctx_hi[(size_t)b*D_+d] = hh;
  *(ushort2*)&ctx_lo[(size_t)b*D_+d] = ll;
}

// ---------------------------------------------------------------------------
// LSTM pointwise: writes bf16 hi/lo h planes + hid planes; c stays fp32.
// ---------------------------------------------------------------------------
__global__ __launch_bounds__(256) void lstm_pointwise(
    const float* __restrict__ gates, const float* __restrict__ WmT,
    const float* __restrict__ WbT,
    const int* __restrict__ midtok, const int* __restrict__ bottok,
    float* __restrict__ c, u16* __restrict__ h_hi, u16* __restrict__ h_lo,
    u16* __restrict__ hidh_s, u16* __restrict__ hidl_s, int s)
{
  const int idx = blockIdx.x*256 + threadIdx.x;   // 0 .. B*H-1
  const int b = idx >> 9;
  const int j = idx & 511;
  const int mt = midtok[b*26 + s];
  const int bt = bottok[b*26 + s];
  const float* wm = WmT + (size_t)mt*2048;
  const float* wb = WbT + (size_t)bt*2048;
  float ig = gates[(size_t)b*2048 + j       ] + wm[j       ] + wb[j       ];
  float fg = gates[(size_t)b*2048 + 512  + j] + wm[512  + j] + wb[512  + j];
  float gg = gates[(size_t)b*2048 + 1024 + j] + wm[1024 + j] + wb[1024 + j];
  float og = gates[(size_t)b*2048 + 1536 + j] + wm[1536 + j] + wb[1536 + j];
  ig = sigmoidf_(ig);
  fg = sigmoidf_(fg);
  gg = tanhf(gg);
  og = sigmoidf_(og);
  const float cn = fg*c[idx] + ig*gg;
  const float hn = og*tanhf(cn);
  c[idx] = cn;
  u16 hh = f2bf_rn(hn), hl = f2bf_rn(hn - bf2f(hh));
  h_hi[idx]=hh; h_lo[idx]=hl;
  hidh_s[idx]=hh; hidl_s[idx]=hl;
}

__global__ __launch_bounds__(256) void bcomb_kernel(
    const float* __restrict__ bh2h, const float* __restrict__ bih,
    const float* __restrict__ bhh, float* __restrict__ o)
{
  int i = blockIdx.x*256 + threadIdx.x;
  if (i < 512) o[i] = bh2h[i];
  else if (i < 2560) o[i] = bih[i-512] + bhh[i-512];
}

extern "C" void kernel_launch(void* const* d_in, const int* in_sizes, int n_in,
                              void* d_out, int out_size, void* d_ws, size_t ws_size,
                              hipStream_t stream) {
  const float* bH   = (const float*)d_in[0];
  const int*   midt = (const int*)  d_in[1];
  const int*   bott = (const int*)  d_in[2];
  const float* Wi2h = (const float*)d_in[3];
  const float* Wh2h = (const float*)d_in[4];
  const float* bh2h = (const float*)d_in[5];
  const float* Wsc  = (const float*)d_in[6];
  const float* Wih  = (const float*)d_in[7];
  const float* Whh  = (const float*)d_in[8];
  const float* bih  = (const float*)d_in[9];
  const float* bhh  = (const float*)d_in[10];
  const float* Wgen = (const float*)d_in[11];
  const float* bgen = (const float*)d_in[12];
  float* out = (float*)d_out;

  char* wp = (char*)d_ws;
  u16* projb  = (u16*)wp; wp += (size_t)B_*T_*H_*2;      // 67.1 MB
  u16* bHb    = (u16*)wp; wp += (size_t)B_*T_*D_*2;      // 67.1 MB
  u16* Bc_hi  = (u16*)wp; wp += (size_t)2560*512*2;
  u16* Bc_lo  = (u16*)wp; wp += (size_t)2560*512*2;
  u16* Wih_hi = (u16*)wp; wp += (size_t)2048*512*2;
  u16* Wih_lo = (u16*)wp; wp += (size_t)2048*512*2;
  u16* Wi2h_h = (u16*)wp; wp += (size_t)512*512*2;
  u16* Wg_hi  = (u16*)wp; wp += (size_t)64*512*2;
  u16* Wg_lo  = (u16*)wp; wp += (size_t)64*512*2;
  u16* h_hi   = (u16*)wp; wp += (size_t)B_*H_*2;
  u16* h_lo   = (u16*)wp; wp += (size_t)B_*H_*2;
  u16* ctx_hi = (u16*)wp; wp += (size_t)B_*D_*2;
  u16* ctx_lo = (u16*)wp; wp += (size_t)B_*D_*2;
  u16* hid_hi = (u16*)wp; wp += (size_t)S_*B_*H_*2;      // 13.6 MB
  u16* hid_lo = (u16*)wp; wp += (size_t)S_*B_*H_*2;      // 13.6 MB
  float* combo = (float*)wp; wp += (size_t)B_*2560*4;
  float* gates = (float*)wp; wp += (size_t)B_*2048*4;
  float* c     = (float*)wp; wp += (size_t)B_*H_*4;
  float* bcomb = (float*)wp; wp += (size_t)2560*4;
  float* WmT   = (float*)wp; wp += (size_t)MID_*2048*4;
  float* WbT   = (float*)wp; wp += (size_t)BOT_*2048*4;
  if ((size_t)(wp - (char*)d_ws) > ws_size) return;  // fail loudly

  hipMemsetAsync(h_hi, 0, (size_t)B_*H_*2, stream);
  hipMemsetAsync(h_lo, 0, (size_t)B_*H_*2, stream);
  hipMemsetAsync(c,    0, (size_t)B_*H_*4, stream);

  bcomb_kernel<<<10, 256, 0, stream>>>(bh2h, bih, bhh, bcomb);
  build_tokT<<<(MID_*2048+255)/256, 256, 0, stream>>>(Wih, WmT, WbT);
  cvt_plane<<<2048, 256, 0, stream>>>(bH, 512, B_*T_, B_*T_, bHb, nullptr);
  cvt_plane<<<64,   256, 0, stream>>>(Wi2h, 512, 512, 512, Wi2h_h, nullptr);
  cvt_plane<<<64,   256, 0, stream>>>(Wh2h, 512, 512, 512, Bc_hi, Bc_lo);
  cvt_plane<<<256,  256, 0, stream>>>(Whh, 512, 2048, 2048, Bc_hi+(size_t)512*512, Bc_lo+(size_t)512*512);
  cvt_plane<<<256,  256, 0, stream>>>(Wih, XL_, 2048, 2048, Wih_hi, Wih_lo);
  cvt_plane<<<16,   256, 0, stream>>>(Wgen, 512, MID_, 64, Wg_hi, Wg_lo);

  // proj = bf16( batch_H @ W_i2h^T ), 1-pass bf16: M=65536, N=512
  gemm_bf<128,128,1><<<dim3(4,512), 256, 32768, stream>>>(
      bHb,nullptr,512, Wi2h_h,nullptr,512,
      nullptr,0,nullptr, nullptr,projb,512, nullptr, 1);

  for (int s=0; s<S_; ++s){
    // combo = [h@W_h2h^T + b_h2h | h@W_hh^T + b_ih + b_hh]  (bf16x2)
    gemm_bf<64,64,0><<<dim3(40,8), 256, 10240, stream>>>(
        h_hi,h_lo,512, Bc_hi,Bc_lo,512,
        nullptr,0,bcomb, combo,nullptr,2560, nullptr, 3);
    attn_kernel<<<B_, 256, 0, stream>>>(projb, combo, Wsc, bH, ctx_hi, ctx_lo);
    // gates = combo[:,512:] + ctx @ W_ih[:, :512]^T  (bf16x2)
    gemm_bf<64,64,0><<<dim3(32,8), 256, 10240, stream>>>(
        ctx_hi,ctx_lo,512, Wih_hi,Wih_lo,512,
        combo+512,2560,nullptr, gates,nullptr,2048, nullptr, 3);
    lstm_pointwise<<<(B_*H_)/256, 256, 0, stream>>>(
        gates, WmT, WbT, midt, bott, c, h_hi, h_lo,
        hid_hi + (size_t)s*B_*H_, hid_lo + (size_t)s*B_*H_, s);
  }

  // out = hid @ W_gen^T + b_gen  (bf16x2), M = S*B = 13312, N=64 (n<38 kept)
  gemm_bf<64,64,2><<<dim3(1,208), 256, 10240, stream>>>(
      hid_hi,hid_lo,512, Wg_hi,Wg_lo,512,
      nullptr,0,nullptr, out,nullptr,0, bgen, 3);
}